// Round 5
// baseline (371.938 us; speedup 1.0000x reference)
//
#include <hip/hip_runtime.h>

// Self-attention (B=8, N=4096, C=128) + residual + inference BatchNorm.
// R5: occupancy attack. Flash split-K x2 (additive partials thanks to no-max
// exp2 softmax) -> grid 1024, 4 blocks/CU, 16 waves/CU. R4's register
// pipeline reverted (compiler spilled it). qkv split by projection with
// 64-row tiles -> 4 blocks/CU. Combine kernel merges partials + residual+BN.
// Falls back to single-pass flash (R3 structure) if ws_size < 59 MB.
//
// ws: Wt 96KB | Qg 8M | Kg 8M | Vtg 8M | Ow 32M | lw 256K  (~59 MB)

typedef __attribute__((ext_vector_type(8))) short bf16x8;
typedef __attribute__((ext_vector_type(4))) float f32x4;

__device__ __forceinline__ unsigned short f2bf(float f) {
  unsigned int u = __builtin_bit_cast(unsigned int, f);
  u += 0x7fffu + ((u >> 16) & 1u);   // RNE
  return (unsigned short)(u >> 16);
}
__device__ __forceinline__ unsigned int pack2(float a, float b) {
  return (unsigned int)f2bf(a) | ((unsigned int)f2bf(b) << 16);
}

// 1/sqrt(128) * log2(e): softmax in exp2 domain; folded into Wq/bq.
#define SCALE_Q (0.08838834764831845f * 1.44269504088896340f)

// ---------------------------------------------------------------------------
// Kernel 1: W[k][n] fp32 -> Wt[n][k] bf16 (Wq pre-scaled)
// ---------------------------------------------------------------------------
__global__ void prep_wt(const float* __restrict__ wq, const float* __restrict__ wk,
                        const float* __restrict__ wv, unsigned short* __restrict__ wt) {
  const float* W = (blockIdx.x == 0) ? wq : (blockIdx.x == 1 ? wk : wv);
  const float sc = (blockIdx.x == 0) ? SCALE_Q : 1.0f;
  unsigned short* out = wt + blockIdx.x * 16384;
  int id = blockIdx.y * 256 + threadIdx.x;
  int n  = id >> 5;
  int kb = (id & 31) * 4;
#pragma unroll
  for (int k = 0; k < 4; ++k)
    out[n * 128 + kb + k] = f2bf(W[(kb + k) * 128 + n] * sc);
}

// ---------------------------------------------------------------------------
// Kernel 2: QKV projection, grid(512, 3): bx = 64-row tile, by = projection.
// x staged swizzled bf16 in LDS; outputs bounce through LDS -> uint4 stores.
// ~34 KB LDS -> 4 blocks/CU.
// ---------------------------------------------------------------------------
__global__ __launch_bounds__(256) void qkv_proj(
    const float* __restrict__ x, const unsigned short* __restrict__ wt,
    const float* __restrict__ bq, const float* __restrict__ bk, const float* __restrict__ bv,
    unsigned short* __restrict__ Qg, unsigned short* __restrict__ Kg,
    unsigned short* __restrict__ Vtg) {
  __shared__ unsigned short xs[64 * 128];    // swizzled bf16 x tile (16 KB)
  __shared__ unsigned short obuf[9216];      // bounce: max(64*136, 128*72) (18 KB)
  const int t = threadIdx.x;
  const int p = blockIdx.y;
  const int rowblk = blockIdx.x * 64;

  // stage x (coalesced float4), swizzled 16B-chunk layout
#pragma unroll
  for (int i = 0; i < 8; ++i) {
    int flat = t * 4 + i * 1024;
    int row = flat >> 7, col = flat & 127;
    float4 v = *(const float4*)(x + (size_t)(rowblk + row) * 128 + col);
    unsigned int u0 = pack2(v.x, v.y), u1 = pack2(v.z, v.w);
    int pos = (col >> 3) ^ (row & 15);
    *(uint2*)(xs + row * 128 + pos * 8 + (col & 7)) = make_uint2(u0, u1);
  }
  __syncthreads();

  const int lane = t & 63, wv_ = t >> 6;
  const int lm = lane & 15, quad = lane >> 4;

  // A fragments: 16 rows per wave
  bf16x8 a[4];
  {
    int row = wv_ * 16 + lm;
#pragma unroll
    for (int ks = 0; ks < 4; ++ks)
      a[ks] = __builtin_bit_cast(bf16x8,
          *(const uint4*)(xs + row * 128 + (((ks * 4 + quad) ^ lm) * 8)));
  }

  const unsigned short* w = wt + p * 16384;
  const float* bias = (p == 0) ? bq : (p == 1 ? bk : bv);
  const float bsc = (p == 0) ? SCALE_Q : 1.0f;

  const f32x4 zero4 = {0.f, 0.f, 0.f, 0.f};
  f32x4 acc[8];
#pragma unroll
  for (int ct = 0; ct < 8; ++ct) acc[ct] = zero4;

#pragma unroll
  for (int ct = 0; ct < 8; ++ct) {
    int n = ct * 16 + lm;
    const uint4* wp = (const uint4*)(w + n * 128 + quad * 8);
#pragma unroll
    for (int ks = 0; ks < 4; ++ks) {
      bf16x8 bfr = __builtin_bit_cast(bf16x8, wp[ks * 4]);
      acc[ct] = __builtin_amdgcn_mfma_f32_16x16x32_bf16(a[ks], bfr, acc[ct], 0, 0, 0);
    }
  }

  const int b   = rowblk >> 12;
  const int nb0 = rowblk & 4095;

  if (p < 2) {
    // obuf[row][c], stride 136 -> coalesced row stores
    int rowb = wv_ * 16 + quad * 4;
#pragma unroll
    for (int ct = 0; ct < 8; ++ct) {
      int c = ct * 16 + lm;
      float bb = bias[c] * bsc;
#pragma unroll
      for (int r = 0; r < 4; ++r)
        obuf[(rowb + r) * 136 + c] = f2bf(acc[ct][r] + bb);
    }
    __syncthreads();
    unsigned short* og = (p == 0) ? Qg : Kg;
    int row = t >> 2;
#pragma unroll
    for (int j = 0; j < 4; ++j) {
      int ch = (t & 3) * 4 + j;
      uint4 vv = *(const uint4*)(obuf + row * 136 + ch * 8);
      *(uint4*)(og + (size_t)(rowblk + row) * 128 + ch * 8) = vv;
    }
  } else {
    // V: obuf[d][key] stride 72 (keys contiguous via acc regs), Vt stores
    int key_base = wv_ * 16 + quad * 4;
#pragma unroll
    for (int ct = 0; ct < 8; ++ct) {
      int c = ct * 16 + lm;
      float bb = bias[c];
      unsigned int u0 = pack2(acc[ct][0] + bb, acc[ct][1] + bb);
      unsigned int u1 = pack2(acc[ct][2] + bb, acc[ct][3] + bb);
      *(uint2*)(obuf + c * 72 + key_base) = make_uint2(u0, u1);
    }
    __syncthreads();
    int d = t >> 1;
#pragma unroll
    for (int j = 0; j < 4; ++j) {
      int ch = (t & 1) * 4 + j;
      uint4 vv = *(const uint4*)(obuf + d * 72 + ch * 8);
      *(uint4*)(Vtg + (size_t)b * 524288 + (size_t)d * 4096 + nb0 + ch * 8) = vv;
    }
  }
}

// ---------------------------------------------------------------------------
// Kernel 3: flash attention. split=1: grid 1024 = 8b x 2 key-halves x 64 qt,
// each block does 16 k-tiles, writes additive partials (Ow, lw).
// split=0: grid 512, full 32 k-tiles + fused epilogue (R3 fallback).
// 256 thr = 4 waves; waves split keys in S-phase, split d in PV-phase.
// ---------------------------------------------------------------------------
__global__ __launch_bounds__(256, 4) void flash_attn(
    const unsigned short* __restrict__ Qg, const unsigned short* __restrict__ Kg,
    const unsigned short* __restrict__ Vtg, const float* __restrict__ x,
    const float* __restrict__ gamma, const float* __restrict__ beta,
    const float* __restrict__ mmean, const float* __restrict__ mvar,
    float* __restrict__ out, float* __restrict__ Ow, float* __restrict__ lw,
    int split) {
  __shared__ uint4 Pb[2048];        // 2 x (64 q x 128 key) bf16, swizzled
  __shared__ float lred[256];

  const int b = blockIdx.x & 7;
  int qt, kt0, ktn, slot;
  if (split) {
    qt  = blockIdx.x >> 4;
    int kh = (blockIdx.x >> 3) & 1;
    kt0 = kh * 16; ktn = 16;
    slot = (b * 64 + qt) * 2 + kh;
  } else {
    qt = blockIdx.x >> 3;
    kt0 = 0; ktn = 32; slot = 0;
  }
  const int t = threadIdx.x;
  const int lane = t & 63;
  const int w = t >> 6;
  const int lm = lane & 15, quad = lane >> 4;
  const int q0 = qt * 64;

  const unsigned short* Qb = Qg  + (size_t)b * 524288;
  const unsigned short* Kb = Kg  + (size_t)b * 524288;
  const unsigned short* Vb = Vtg + (size_t)b * 524288;

  // Q as B-fragments, register-resident
  bf16x8 qf[4][4];
#pragma unroll
  for (int nt = 0; nt < 4; ++nt) {
    const uint4* qp = (const uint4*)(Qb + (size_t)(q0 + nt * 16 + lm) * 128 + quad * 8);
#pragma unroll
    for (int ks = 0; ks < 4; ++ks) qf[nt][ks] = __builtin_bit_cast(bf16x8, qp[ks * 4]);
  }

  const f32x4 zero4 = {0.f, 0.f, 0.f, 0.f};
  f32x4 o[2][4];
#pragma unroll
  for (int mt = 0; mt < 2; ++mt)
#pragma unroll
    for (int nt = 0; nt < 4; ++nt) o[mt][nt] = zero4;
  float lp[4] = {0.f, 0.f, 0.f, 0.f};

#pragma unroll 1
  for (int kti = 0; kti < ktn; ++kti) {
    const int key0 = (kt0 + kti) * 128;

    // K rows (wave's 32 keys) and V^T rows (wave's 32 d) as A-frags from L2
    bf16x8 kf[2][4], vf[2][4];
#pragma unroll
    for (int mt = 0; mt < 2; ++mt) {
      const uint4* kp = (const uint4*)(Kb + (size_t)(key0 + w * 32 + mt * 16 + lm) * 128 + quad * 8);
      const uint4* vp = (const uint4*)(Vb + (size_t)(w * 32 + mt * 16 + lm) * 4096 + key0 + quad * 8);
#pragma unroll
      for (int ks = 0; ks < 4; ++ks) {
        kf[mt][ks] = __builtin_bit_cast(bf16x8, kp[ks * 4]);
        vf[mt][ks] = __builtin_bit_cast(bf16x8, vp[ks * 4]);
      }
    }

    // S^T = K * Q^T : row = key (quad*4+r), col = q (lm)
    f32x4 sa[2][4];
#pragma unroll
    for (int mt = 0; mt < 2; ++mt)
#pragma unroll
      for (int nt = 0; nt < 4; ++nt) sa[mt][nt] = zero4;
#pragma unroll
    for (int ks = 0; ks < 4; ++ks)
#pragma unroll
      for (int mt = 0; mt < 2; ++mt)
#pragma unroll
        for (int nt = 0; nt < 4; ++nt)
          sa[mt][nt] = __builtin_amdgcn_mfma_f32_16x16x32_bf16(kf[mt][ks], qf[nt][ks], sa[mt][nt], 0, 0, 0);

    // no-max softmax: P = exp2(S~)
    unsigned short* Ps = (unsigned short*)(Pb + (kti & 1) * 1024);
    const int sub = (quad & 1) * 4;
#pragma unroll
    for (int mt = 0; mt < 2; ++mt) {
      int c16 = w * 4 + mt * 2 + (quad >> 1);
      int pos = c16 ^ lm;
#pragma unroll
      for (int nt = 0; nt < 4; ++nt) {
        float e0 = exp2f(sa[mt][nt][0]), e1 = exp2f(sa[mt][nt][1]);
        float e2 = exp2f(sa[mt][nt][2]), e3 = exp2f(sa[mt][nt][3]);
        lp[nt] += (e0 + e1) + (e2 + e3);
        *(uint2*)(Ps + (nt * 16 + lm) * 128 + pos * 8 + sub) =
            make_uint2(pack2(e0, e1), pack2(e2, e3));
      }
    }
    __syncthreads();   // P complete (also fences dbuf reuse)

    // O^T += V^T * P^T
    const uint4* Pr = Pb + (kti & 1) * 1024;
#pragma unroll
    for (int nt = 0; nt < 4; ++nt) {
      bf16x8 pf[4];
#pragma unroll
      for (int ks = 0; ks < 4; ++ks)
        pf[ks] = __builtin_bit_cast(bf16x8, Pr[(nt * 16 + lm) * 16 + ((ks * 4 + quad) ^ lm)]);
#pragma unroll
      for (int ks = 0; ks < 4; ++ks)
#pragma unroll
        for (int mt = 0; mt < 2; ++mt)
          o[mt][nt] = __builtin_amdgcn_mfma_f32_16x16x32_bf16(vf[mt][ks], pf[ks], o[mt][nt], 0, 0, 0);
    }
  }

  // l reduction: across quads (keys), then across waves (key slices)
#pragma unroll
  for (int nt = 0; nt < 4; ++nt) {
    lp[nt] += __shfl_xor(lp[nt], 16);
    lp[nt] += __shfl_xor(lp[nt], 32);
  }
  if (quad == 0) {
#pragma unroll
    for (int nt = 0; nt < 4; ++nt) lred[w * 64 + nt * 16 + lm] = lp[nt];
  }
  __syncthreads();

  if (split) {
    // store partial l (block's key range) and partial O^T sums
    if (t < 64)
      lw[slot * 64 + t] = (lred[t] + lred[64 + t]) + (lred[128 + t] + lred[192 + t]);
    float* Op = Ow + (size_t)slot * 8192;
#pragma unroll
    for (int mt = 0; mt < 2; ++mt) {
      int c0 = w * 32 + mt * 16 + quad * 4;
#pragma unroll
      for (int nt = 0; nt < 4; ++nt) {
        float4 ov;
        ov.x = o[mt][nt][0]; ov.y = o[mt][nt][1];
        ov.z = o[mt][nt][2]; ov.w = o[mt][nt][3];
        *(float4*)(Op + (nt * 16 + lm) * 128 + c0) = ov;
      }
    }
    return;
  }

  float rl[4];
#pragma unroll
  for (int nt = 0; nt < 4; ++nt) {
    int q = nt * 16 + lm;
    rl[nt] = 1.0f / ((lred[q] + lred[64 + q]) + (lred[128 + q] + lred[192 + q]));
  }

  // fused epilogue (non-split): 1/l, residual, BN
#pragma unroll
  for (int mt = 0; mt < 2; ++mt) {
    int c0 = w * 32 + mt * 16 + quad * 4;
    float4 gm = *(const float4*)(gamma + c0);
    float4 bt = *(const float4*)(beta + c0);
    float4 mm = *(const float4*)(mmean + c0);
    float4 mv = *(const float4*)(mvar + c0);
    float iv0 = gm.x * rsqrtf(mv.x + 1e-3f), iv1 = gm.y * rsqrtf(mv.y + 1e-3f);
    float iv2 = gm.z * rsqrtf(mv.z + 1e-3f), iv3 = gm.w * rsqrtf(mv.w + 1e-3f);
    float ad0 = bt.x - mm.x * iv0, ad1 = bt.y - mm.y * iv1;
    float ad2 = bt.z - mm.z * iv2, ad3 = bt.w - mm.w * iv3;
#pragma unroll
    for (int nt = 0; nt < 4; ++nt) {
      size_t g = ((size_t)b * 4096 + q0 + nt * 16 + lm) * 128 + c0;
      float4 xr = *(const float4*)(x + g);
      float4 ov;
      ov.x = (o[mt][nt][0] * rl[nt] + xr.x) * iv0 + ad0;
      ov.y = (o[mt][nt][1] * rl[nt] + xr.y) * iv1 + ad1;
      ov.z = (o[mt][nt][2] * rl[nt] + xr.z) * iv2 + ad2;
      ov.w = (o[mt][nt][3] * rl[nt] + xr.w) * iv3 + ad3;
      *(float4*)(out + g) = ov;
    }
  }
}

// ---------------------------------------------------------------------------
// Kernel 4: combine split-K partials + residual + BN. grid 4096 x 256 thr.
// ---------------------------------------------------------------------------
__global__ __launch_bounds__(256) void combine(
    const float* __restrict__ Ow, const float* __restrict__ lw,
    const float* __restrict__ x,
    const float* __restrict__ gamma, const float* __restrict__ beta,
    const float* __restrict__ mmean, const float* __restrict__ mvar,
    float* __restrict__ out) {
  int flat4 = blockIdx.x * 256 + threadIdx.x;
  int g  = flat4 * 4;
  int row = g >> 7;          // b*4096 + n
  int c0  = g & 127;
  int bq = row >> 12;
  int n  = row & 4095;
  int qt = n >> 6, qq = n & 63;
  int slot = (bq * 64 + qt) * 2;

  float l = lw[slot * 64 + qq] + lw[(slot + 1) * 64 + qq];
  float rl = 1.0f / l;
  float4 O0 = *(const float4*)(Ow + (size_t)slot * 8192 + qq * 128 + c0);
  float4 O1 = *(const float4*)(Ow + (size_t)(slot + 1) * 8192 + qq * 128 + c0);
  float4 gm = *(const float4*)(gamma + c0);
  float4 bt = *(const float4*)(beta + c0);
  float4 mm = *(const float4*)(mmean + c0);
  float4 mv = *(const float4*)(mvar + c0);
  float iv0 = gm.x * rsqrtf(mv.x + 1e-3f), iv1 = gm.y * rsqrtf(mv.y + 1e-3f);
  float iv2 = gm.z * rsqrtf(mv.z + 1e-3f), iv3 = gm.w * rsqrtf(mv.w + 1e-3f);
  float4 xr = *(const float4*)(x + g);
  float4 ov;
  ov.x = ((O0.x + O1.x) * rl + xr.x) * iv0 + (bt.x - mm.x * iv0);
  ov.y = ((O0.y + O1.y) * rl + xr.y) * iv1 + (bt.y - mm.y * iv1);
  ov.z = ((O0.z + O1.z) * rl + xr.z) * iv2 + (bt.z - mm.z * iv2);
  ov.w = ((O0.w + O1.w) * rl + xr.w) * iv3 + (bt.w - mm.w * iv3);
  *(float4*)(out + g) = ov;
}

// ---------------------------------------------------------------------------
extern "C" void kernel_launch(void* const* d_in, const int* in_sizes, int n_in,
                              void* d_out, int out_size, void* d_ws, size_t ws_size,
                              hipStream_t stream) {
  const float* x     = (const float*)d_in[0];
  const float* wq    = (const float*)d_in[1];
  const float* bq    = (const float*)d_in[2];
  const float* wk    = (const float*)d_in[3];
  const float* bk    = (const float*)d_in[4];
  const float* wv    = (const float*)d_in[5];
  const float* bv    = (const float*)d_in[6];
  const float* gamma = (const float*)d_in[7];
  const float* beta  = (const float*)d_in[8];
  const float* mmean = (const float*)d_in[9];
  const float* mvar  = (const float*)d_in[10];
  float* out = (float*)d_out;

  unsigned short* wt  = (unsigned short*)d_ws;
  unsigned short* Qg  = wt + 3 * 128 * 128;
  unsigned short* Kg  = Qg + 8 * 4096 * 128;
  unsigned short* Vtg = Kg + 8 * 4096 * 128;
  float* Ow = (float*)(Vtg + 8 * 4096 * 128);   // 1024 slots x 64 x 128 fp32
  float* lw = Ow + 1024 * 8192;                 // 1024 slots x 64 fp32

  const size_t need = 98304ull + 3ull * 8388608ull + 33554432ull + 262144ull;
  const int split = (ws_size >= need) ? 1 : 0;

  prep_wt<<<dim3(3, 16), dim3(256), 0, stream>>>(wq, wk, wv, wt);
  qkv_proj<<<dim3(512, 3), dim3(256), 0, stream>>>(x, wt, bq, bk, bv, Qg, Kg, Vtg);
  if (split) {
    flash_attn<<<dim3(1024), dim3(256), 0, stream>>>(Qg, Kg, Vtg, x, gamma, beta,
                                                     mmean, mvar, out, Ow, lw, 1);
    combine<<<dim3(4096), dim3(256), 0, stream>>>(Ow, lw, x, gamma, beta, mmean, mvar, out);
  } else {
    flash_attn<<<dim3(512), dim3(256), 0, stream>>>(Qg, Kg, Vtg, x, gamma, beta,
                                                    mmean, mvar, out, Ow, lw, 0);
  }
}